// Round 11
// baseline (100671.185 us; speedup 1.0000x reference)
//
#include <hip/hip_runtime.h>

// GRU, round 11: row-per-wave layout -- one barrier/step, no gsum round trip.
//
// r10 showed IG-hoist + no-vmcnt barriers = exact r7 parity -> step is
// transport-dominated; the only removable non-transport term left is the
// cross-wave gate assembly (sync2 + gsum LDS round trip, ~0.15us).
// New layout: 64 WGs x 8 rows, ONE ROW PER WAVE (wv 0..7):
//   lanes 0..47 = 3 gates x 16 k-lanes, 32 f32 whh/lane (proven residency);
//   after shfl_xor k-reduce, hr/hz/hn live in lane-groups 0/1/2 of the SAME
//   wave -> 3 uniform shuffles assemble the gates; gates computed
//   wave-uniformly; lane 0 stores. No gsum, no second barrier.
// Comm: 1 value per 16B line {val,tag,val,tag} (same CHECK macro), 512 lines,
//   parity double-buffered; 8 poller waves (wv 8..15), 1 line each, fresh
//   4-deep pipelined ring per step (r7-proven); sc0+sc1 system scope.
// Barriers: raw lgkmcnt-only s_barrier (no vmcnt drain; ring + store-acks
//   persist). IG hoisted by GEMM (r8-proven), bias folded; per-wave uniform
//   IG prefetch for t+1 issued after the store (consumed a full step later).
// Poll guard -> fast wrong-answer on comm failure, never a hang.

#define T_STEPS    32768
#define INSZ       256
#define HSZ        512
#define NWG        64
#define RPW        8          // rows per WG
#define TPB        1024       // 8 mv waves + 8 poller waves
#define POLL_GUARD 16384

typedef unsigned long long u64;
typedef unsigned int u32;
typedef u32 u32x4 __attribute__((ext_vector_type(4)));
typedef float f32x4 __attribute__((ext_vector_type(4)));
typedef float f32x2 __attribute__((ext_vector_type(2)));

// h_lds pad: +4 floats per 32 (16B-aligned chunks, rotates bank groups)
__device__ __forceinline__ int hpad(int k) { return k + 4 * (k >> 5); }

__device__ __forceinline__ void st16_sys(u64* p, u32x4 v) {
  asm volatile("global_store_dwordx4 %0, %1, off sc0 sc1" :: "v"(p), "v"(v) : "memory");
}

// raw workgroup barrier: flush LDS ops (lgkm) but do NOT drain vmcnt.
__device__ __forceinline__ void barrier_lds_only() {
  asm volatile("s_waitcnt lgkmcnt(0)\n\ts_barrier" ::: "memory");
}

// Re-init every call (harness does not re-poison d_ws between graph replays).
// Comm layout: parity buffer = 512 lines x 16B; line j = {h[j], tag, h[j], tag}.
__global__ void init_comm(u64* __restrict__ comm, const float* __restrict__ h0) {
  int jj = threadIdx.x;                      // 0..511
  u64 v0 = (u64)__float_as_uint(h0[jj]);     // {val, tag=0}
  comm[2 * jj]            = v0;
  comm[2 * jj + 1]        = v0;
  comm[1024 + 2 * jj]     = 0xFFFFFFFF00000000ull;   // buf1: invalid tag
  comm[1024 + 2 * jj + 1] = 0xFFFFFFFF00000000ull;
}

// ---------------- Phase 1: igates GEMM (64x64 tiles, K=256; r8-proven) -----
__launch_bounds__(256)
__global__ void igates_gemm(const float* __restrict__ input,
                            const float* __restrict__ w_ih,
                            const float* __restrict__ bias,
                            float* __restrict__ ig)
{
  const int t0 = blockIdx.x * 64;
  const int r0 = blockIdx.y * 64;
  const int tid = threadIdx.x;
  const int tx = tid & 15, ty = tid >> 4;
  __shared__ float As[64][68];
  __shared__ float Bs[64][68];
  float acc[4][4] = {};
  for (int kc = 0; kc < INSZ; kc += 64) {
    #pragma unroll
    for (int i = 0; i < 4; ++i) {
      const int rr = (tid >> 4) + 16 * i;
      f32x4 av = *(const f32x4*)&input[(size_t)(t0 + rr) * INSZ + kc + tx * 4];
      *(f32x4*)&As[rr][tx * 4] = av;
      f32x4 bv = *(const f32x4*)&w_ih[(size_t)(r0 + rr) * INSZ + kc + tx * 4];
      #pragma unroll
      for (int ci = 0; ci < 4; ++ci) Bs[tx * 4 + ci][rr] = bv[ci];
    }
    __syncthreads();
    #pragma unroll 16
    for (int kk = 0; kk < 64; ++kk) {
      float av[4], bv[4];
      #pragma unroll
      for (int a = 0; a < 4; ++a) av[a] = As[ty * 4 + a][kk];
      #pragma unroll
      for (int b = 0; b < 4; ++b) bv[b] = Bs[kk][tx * 4 + b];
      #pragma unroll
      for (int a = 0; a < 4; ++a)
        #pragma unroll
        for (int b = 0; b < 4; ++b) acc[a][b] += av[a] * bv[b];
    }
    __syncthreads();
  }
  #pragma unroll
  for (int a = 0; a < 4; ++a)
    #pragma unroll
    for (int b = 0; b < 4; ++b) {
      const int r = r0 + tx * 4 + b;
      ig[(size_t)(t0 + ty * 4 + a) * 1536 + r] = acc[a][b] + bias[r];
    }
}

// ---------------- Phase 2: persistent recurrence (row-per-wave) -------------
__launch_bounds__(TPB, 1)
__global__ void gru_fast(const float* __restrict__ IG,     // [T][1536], bias folded
                         const float* __restrict__ init_hidden,
                         const float* __restrict__ w_hh,
                         const float* __restrict__ bias_n,
                         u64* __restrict__ comm,
                         float* __restrict__ out)
{
  const int tid  = threadIdx.x;
  const int wg   = blockIdx.x;
  const int wv   = tid >> 6;                 // 0..15
  const int lane = tid & 63;
  const bool pol = (wv >= 8);
  const int  pt  = (wv - 8) * 64 + lane;     // poller line 0..511 (iff pol)

  const int j  = wg * RPW + wv;              // owned h row (iff !pol)
  const int q  = lane >> 4;                  // gate 0..2 (3 = idle lanes)
  const int kl = lane & 15;                  // k-lane 0..15

  // ---- whh: 32 f32/lane (8 quads) -- proven residency sweet spot ----
  f32x4 whh[8];
  if (!pol && lane < 48) {
    const float* rp = w_hh + (size_t)(j + 512 * q) * HSZ + kl * 32;
    #pragma unroll
    for (int c = 0; c < 8; ++c) whh[c] = *(const f32x4*)(rp + c * 4);
  }
  // ---- wave-uniform row state (broadcast loads; valid iff !pol) ----
  float hold = 0.f, bn = 0.f, ig_r = 0.f, ig_z = 0.f, ig_n = 0.f;
  if (!pol) {
    hold = init_hidden[j];
    bn   = bias_n[j];
    ig_r = IG[j];
    ig_z = IG[512 + j];
    ig_n = IG[1024 + j];
  }

  __shared__ float h_lds[2][HSZ + 4 * (HSZ >> 5)];

  u32x4 pa, pb, pc, pd, win;

#define ISSUE(Rr) \
  asm volatile("global_load_dwordx4 %0, %1, off sc0 sc1" : "=&v"(Rr) : "v"(lp) : "memory")
#define CHECK(Rr) \
  asm volatile("s_waitcnt vmcnt(3)" : "+v"(Rr)); \
  __builtin_amdgcn_sched_barrier(0); \
  if ((Rr[1] == tt && Rr[3] == tt) || --guard == 0) { win = Rr; break; } \
  ISSUE(Rr)

  for (int t = 0; t < T_STEPS; ++t) {
    const int p  = t & 1;
    const u32 tt = (u32)t;

    // ---- poll h_t (dedicated waves; vmcnt queue = poll loads only) ----
    if (pol) {
      const u64* lp = comm + (size_t)p * 1024 + 2 * pt;
      ISSUE(pa); ISSUE(pb); ISSUE(pc); ISSUE(pd);
      int guard = POLL_GUARD;
      win = pa;
      for (;;) {
        CHECK(pa);
        CHECK(pb);
        CHECK(pc);
        CHECK(pd);
      }
      h_lds[p][hpad(pt)] = __uint_as_float(win[0]);
    }
    barrier_lds_only();   // the ONLY barrier per step (no vmcnt drain)

    if (!pol) {
      // ---- hh matvec: 32 MAC per lane; k-reduce within 16-lane group ----
      float a = 0.f;
      const float* hp = &h_lds[p][kl * 36];   // hpad(32*kl)
      #pragma unroll
      for (int c = 0; c < 8; ++c) {
        f32x4 hv4 = *(const f32x4*)(hp + c * 4);
        #pragma unroll
        for (int u = 0; u < 4; ++u) a += whh[c][u] * hv4[u];
      }
      a += __shfl_xor(a, 1);
      a += __shfl_xor(a, 2);
      a += __shfl_xor(a, 4);
      a += __shfl_xor(a, 8);
      // gate assembly: hr/hz/hn in lane-groups 0/1/2 of THIS wave
      const float hr = __shfl(a, 0);
      const float hz = __shfl(a, 16);
      const float hn = __shfl(a, 32);
      // wave-uniform gates (fast exp/rcp math; r7-proven accuracy)
      const float reset = __builtin_amdgcn_rcpf(1.0f + __expf(-(ig_r + hr)));
      const float upd   = __builtin_amdgcn_rcpf(1.0f + __expf(-(ig_z + hz)));
      const float e2    = __expf(2.0f * (ig_n + reset * (hn + bn)));
      const float newv  = 1.0f - 2.0f * __builtin_amdgcn_rcpf(1.0f + e2);
      const float hnew  = newv + upd * (hold - newv);
      hold = hnew;
      if (lane == 0) {
        u64* nbuf = comm + (size_t)((t + 1) & 1) * 1024;
        u32x4 pk;
        pk[0] = __float_as_uint(hnew);  pk[1] = (u32)(t + 1);
        pk[2] = __float_as_uint(hnew);  pk[3] = (u32)(t + 1);
        st16_sys(nbuf + 2 * j, pk);
        if (wg == 0 && wv == 0) out[t] = hnew;
      }
      // IG prefetch for t+1 (wave-uniform; consumed a full step later)
      const size_t bse = (size_t)((t + 1 < T_STEPS) ? (t + 1) : t) * 1536;
      ig_r = IG[bse + j];
      ig_z = IG[bse + 512 + j];
      ig_n = IG[bse + 1024 + j];
    }
  }
#undef ISSUE
#undef CHECK
  asm volatile("s_waitcnt vmcnt(0)" ::: "memory");   // drain before endpgm
}

// ---------------- Fallback: proven round-7 kernel (ws too small) ------------
#define TPB_FB 1024
__device__ __forceinline__ int xpad(int k) { return k + ((k >> 4) << 2); }
__device__ __forceinline__ float grp_reduce16(float v) {
  v += __shfl_xor(v, 1);
  v += __shfl_xor(v, 2);
  v += __shfl_xor(v, 4);
  v += __shfl_xor(v, 8);
  return v;
}

__launch_bounds__(TPB_FB, 1)
__global__ void gru_persistent_fb(const float* __restrict__ input,
                                  const float* __restrict__ init_hidden,
                                  const float* __restrict__ w_ih,
                                  const float* __restrict__ w_hh,
                                  const float* __restrict__ bias,
                                  const float* __restrict__ bias_n,
                                  u64* __restrict__ comm,
                                  float* __restrict__ out)
{
  const int tid = threadIdx.x;
  const int wg  = blockIdx.x;
  const int g   = tid >> 4;
  const int l   = tid & 15;
  const bool mv = (g < 48);
  const int R   = wg * 16 + (g & 15) + 512 * (g >> 4);

  f32x4 whh[8];
  f32x4 wih[4];
  if (mv) {
    const float* rp = w_hh + (size_t)R * HSZ + l * 32;
    #pragma unroll
    for (int c = 0; c < 8; ++c) whh[c] = *(const f32x4*)(rp + c * 4);
    const float* rp2 = w_ih + (size_t)R * INSZ + l * 16;
    #pragma unroll
    for (int c = 0; c < 4; ++c) wih[c] = *(const f32x4*)(rp2 + c * 4);
  }
  float hold = 0.f, b_r = 0.f, b_z = 0.f, b_n = 0.f, bn = 0.f;
  if (tid < 16) {
    const int j = wg * 16 + tid;
    hold = init_hidden[j];
    b_r  = bias[j]; b_z = bias[j + 512]; b_n = bias[j + 1024];
    bn   = bias_n[j];
  }
  __shared__ float h_lds[2][HSZ + 4 * (HSZ >> 5)];
  __shared__ float gsum[48];
  __shared__ float isum[2][48];
  __shared__ float xstage[INSZ + (INSZ >> 4) * 4];

  if (tid >= 64 && tid < 128) {
    const int s = tid - 64;
    f32x4 v = *(const f32x4*)(input + s * 4);
    *(f32x4*)&xstage[xpad(s * 4)] = v;
  }
  __syncthreads();
  if (mv) {
    float a = 0.f;
    #pragma unroll
    for (int c = 0; c < 4; ++c) {
      f32x4 xv = *(const f32x4*)&xstage[20 * l + 4 * c];
      #pragma unroll
      for (int u = 0; u < 4; ++u) a += wih[c][u] * xv[u];
    }
    a = grp_reduce16(a);
    if (l == 0) isum[0][g] = a;
  }
  const bool poller = (tid >= 768);
  const int  pt     = tid - 768;
  u32x4 pa, pb, pc, pd, win;

#define ISSUE(Rr) \
  asm volatile("global_load_dwordx4 %0, %1, off sc0 sc1" : "=&v"(Rr) : "v"(lp) : "memory")
#define CHECK(Rr) \
  asm volatile("s_waitcnt vmcnt(3)" : "+v"(Rr)); \
  __builtin_amdgcn_sched_barrier(0); \
  if ((Rr[1] == tt && Rr[3] == tt) || --guard == 0) { win = Rr; break; } \
  ISSUE(Rr)

  for (int t = 0; t < T_STEPS; ++t) {
    const int p  = t & 1;
    const u32 tt = (u32)t;
    f32x4 xnew = {0.f, 0.f, 0.f, 0.f};
    if (tid >= 64 && tid < 128) {
      const int tn = (t + 1 < T_STEPS) ? (t + 1) : (T_STEPS - 1);
      xnew = *(const f32x4*)(input + (size_t)tn * INSZ + (tid - 64) * 4);
    }
    if (poller) {
      const u64* lp = comm + (size_t)p * HSZ + 2 * pt;
      ISSUE(pa); ISSUE(pb); ISSUE(pc); ISSUE(pd);
      int guard = POLL_GUARD;
      win = pa;
      for (;;) {
        CHECK(pa);
        CHECK(pb);
        CHECK(pc);
        CHECK(pd);
      }
      f32x2 hv;
      hv[0] = __uint_as_float(win[0]);
      hv[1] = __uint_as_float(win[2]);
      *(f32x2*)&h_lds[p][hpad(2 * pt)] = hv;
    }
    __syncthreads();
    if (mv) {
      float a = 0.f;
      const float* hp = &h_lds[p][l * 36];
      #pragma unroll
      for (int c = 0; c < 8; ++c) {
        f32x4 hv4 = *(const f32x4*)(hp + c * 4);
        #pragma unroll
        for (int u = 0; u < 4; ++u) a += whh[c][u] * hv4[u];
      }
      a = grp_reduce16(a);
      if (l == 0) gsum[g] = a;
    }
    if (tid >= 64 && tid < 128) *(f32x4*)&xstage[xpad((tid - 64) * 4)] = xnew;
    __syncthreads();
    if (tid < 16) {
      const int j = tid;
      const float hr = gsum[j], hz = gsum[16 + j], hn = gsum[32 + j];
      const float i_r = isum[p][j], i_z = isum[p][16 + j], i_n = isum[p][32 + j];
      const float reset = __builtin_amdgcn_rcpf(1.0f + __expf(-(i_r + b_r + hr)));
      const float upd   = __builtin_amdgcn_rcpf(1.0f + __expf(-(i_z + b_z + hz)));
      const float e2    = __expf(2.0f * (i_n + b_n + reset * (hn + bn)));
      const float newv  = 1.0f - 2.0f * __builtin_amdgcn_rcpf(1.0f + e2);
      const float hnew  = newv + upd * (hold - newv);
      hold = hnew;
      const float hpair = __shfl(hnew, tid + 1);
      if ((j & 1) == 0) {
        u64* nbuf = comm + (size_t)((t + 1) & 1) * HSZ;
        u32x4 pk;
        pk[0] = __float_as_uint(hnew);  pk[1] = (u32)(t + 1);
        pk[2] = __float_as_uint(hpair); pk[3] = (u32)(t + 1);
        st16_sys(&nbuf[wg * 16 + j], pk);
        if (wg == 0 && j == 0) out[t] = hnew;
      }
    }
    if (mv) {
      float a2 = 0.f;
      #pragma unroll
      for (int c = 0; c < 4; ++c) {
        f32x4 xv = *(const f32x4*)&xstage[20 * l + 4 * c];
        #pragma unroll
        for (int u = 0; u < 4; ++u) a2 += wih[c][u] * xv[u];
      }
      a2 = grp_reduce16(a2);
      if (l == 0) isum[(t + 1) & 1][g] = a2;
    }
  }
#undef ISSUE
#undef CHECK
}

extern "C" void kernel_launch(void* const* d_in, const int* in_sizes, int n_in,
                              void* d_out, int out_size, void* d_ws, size_t ws_size,
                              hipStream_t stream) {
  const float* input  = (const float*)d_in[0];
  const float* h0     = (const float*)d_in[1];
  const float* w_ih   = (const float*)d_in[2];
  const float* w_hh   = (const float*)d_in[3];
  const float* bias   = (const float*)d_in[4];
  const float* bias_n = (const float*)d_in[5];
  float* out = (float*)d_out;

  const size_t IG_BYTES = (size_t)T_STEPS * 1536 * sizeof(float);  // 201.3 MB

  if (ws_size >= IG_BYTES + 32768) {
    float* ig  = (float*)d_ws;
    u64*  comm = (u64*)((char*)d_ws + IG_BYTES);   // 2 parity x 1024 u64 = 16 KB
    hipLaunchKernelGGL(init_comm, dim3(1), dim3(HSZ), 0, stream, comm, h0);
    hipLaunchKernelGGL(igates_gemm, dim3(T_STEPS / 64, 1536 / 64), dim3(256),
                       0, stream, input, w_ih, bias, ig);
    hipLaunchKernelGGL(gru_fast, dim3(NWG), dim3(TPB), 0, stream,
                       ig, h0, w_hh, bias_n, comm, out);
  } else {
    u64* comm = (u64*)d_ws;
    hipLaunchKernelGGL(init_comm, dim3(1), dim3(HSZ), 0, stream, comm, h0);
    hipLaunchKernelGGL(gru_persistent_fb, dim3(NWG / 2), dim3(TPB_FB), 0, stream,
                       input, h0, w_ih, w_hh, bias, bias_n, comm, out);
  }
}

// Round 14
// 52675.269 us; speedup vs baseline: 1.9112x; 1.9112x over previous
//
#include <hip/hip_runtime.h>

// GRU, round 14: return to the never-failed semantics.
// = r10 kernel with __syncthreads() restored at both barriers.
//
// r12/r13 post-mortem: lgkm-only barriers left the gate wave's comm store
// un-drained; two iterations later the SAME wave stores a newer tag to the
// SAME address with the old store potentially still in flight. VMEM stores
// are unordered without s_waitcnt -> the line can permanently regress to the
// older tag -> consumer guard expiry -> stale accept (probabilistic wrong
// answer: r12 post-timing, r13 first-call). __syncthreads' implicit vmcnt(0)
// drain closes this (r1-r7: 6/6 passes), and r10 showed lgkm-only barriers
// bought ZERO time (51.8 ms either way). Keep the IG-hoist (neutral on time,
// removes ~1 GB input re-stream, absmax-friendly).
//
// Structure (proven): igates hoisted to a GEMM (bias folded); persistent
// recurrence 32 WGs x 1024: 48 gate-rows x 16 lanes matvec with 32 f32
// whh/lane register-resident; dedicated poller waves (tid>=768) with 4-deep
// pipelined tag ring; one coalesced 8x16B tagged store burst per WG; parity
// double-buffered comm; tagged 8B words {val|step}, 2 per 16B line; sc0+sc1.

#define T_STEPS    32768
#define INSZ       256
#define HSZ        512
#define NWG        32
#define TPB        1024
#define POLL_GUARD 65536

typedef unsigned long long u64;
typedef unsigned int u32;
typedef u32 u32x4 __attribute__((ext_vector_type(4)));
typedef float f32x4 __attribute__((ext_vector_type(4)));
typedef float f32x2 __attribute__((ext_vector_type(2)));

__device__ __forceinline__ float grp_reduce16(float v) {
  v += __shfl_xor(v, 1);
  v += __shfl_xor(v, 2);
  v += __shfl_xor(v, 4);
  v += __shfl_xor(v, 8);
  return v;
}

// h_lds pad: +4 floats per 32 (16B-aligned, rotates bank groups)
__device__ __forceinline__ int hpad(int k) { return k + 4 * (k >> 5); }

__device__ __forceinline__ void st16_sys(u64* p, u32x4 v) {
  asm volatile("global_store_dwordx4 %0, %1, off sc0 sc1" :: "v"(p), "v"(v) : "memory");
}

// Re-init every call (harness does not re-poison d_ws between graph replays).
__global__ void init_comm(u64* __restrict__ comm, const float* __restrict__ h0) {
  int jj = threadIdx.x;                      // 0..511
  u32 bits = __float_as_uint(h0[jj]);
  comm[jj]       = (u64)bits;                // buf0: tag 0 | h0 value
  comm[HSZ + jj] = 0xFFFFFFFF00000000ull;    // buf1: invalid tag
}

// ---------------- Phase 1: igates GEMM (64x64 tiles, K=256; r8-proven) -----
__launch_bounds__(256)
__global__ void igates_gemm(const float* __restrict__ input,
                            const float* __restrict__ w_ih,
                            const float* __restrict__ bias,
                            float* __restrict__ ig)
{
  const int t0 = blockIdx.x * 64;
  const int r0 = blockIdx.y * 64;
  const int tid = threadIdx.x;
  const int tx = tid & 15, ty = tid >> 4;
  __shared__ float As[64][68];
  __shared__ float Bs[64][68];
  float acc[4][4] = {};
  for (int kc = 0; kc < INSZ; kc += 64) {
    #pragma unroll
    for (int i = 0; i < 4; ++i) {
      const int rr = (tid >> 4) + 16 * i;
      f32x4 av = *(const f32x4*)&input[(size_t)(t0 + rr) * INSZ + kc + tx * 4];
      *(f32x4*)&As[rr][tx * 4] = av;
      f32x4 bv = *(const f32x4*)&w_ih[(size_t)(r0 + rr) * INSZ + kc + tx * 4];
      #pragma unroll
      for (int ci = 0; ci < 4; ++ci) Bs[tx * 4 + ci][rr] = bv[ci];
    }
    __syncthreads();
    #pragma unroll 16
    for (int kk = 0; kk < 64; ++kk) {
      float av[4], bv[4];
      #pragma unroll
      for (int a = 0; a < 4; ++a) av[a] = As[ty * 4 + a][kk];
      #pragma unroll
      for (int b = 0; b < 4; ++b) bv[b] = Bs[kk][tx * 4 + b];
      #pragma unroll
      for (int a = 0; a < 4; ++a)
        #pragma unroll
        for (int b = 0; b < 4; ++b) acc[a][b] += av[a] * bv[b];
    }
    __syncthreads();
  }
  #pragma unroll
  for (int a = 0; a < 4; ++a)
    #pragma unroll
    for (int b = 0; b < 4; ++b) {
      const int r = r0 + tx * 4 + b;
      ig[(size_t)(t0 + ty * 4 + a) * 1536 + r] = acc[a][b] + bias[r];
    }
}

// ---------------- Phase 2: persistent recurrence ----------------
__launch_bounds__(TPB, 1)
__global__ void gru_fast(const float* __restrict__ IG,     // [T][1536], bias folded
                         const float* __restrict__ init_hidden,
                         const float* __restrict__ w_hh,
                         const float* __restrict__ bias_n,
                         u64* __restrict__ comm,
                         float* __restrict__ out)
{
  const int tid = threadIdx.x;
  const int wg  = blockIdx.x;
  const int g   = tid >> 4;                             // 0..63
  const int l   = tid & 15;
  const bool mv = (g < 48);                             // matvec threads
  const int R   = wg * 16 + (g & 15) + 512 * (g >> 4);  // valid iff mv

  // ---- whh: 32 f32/lane (8 quads) -- the proven residency sweet spot ----
  f32x4 whh[8];
  if (mv) {
    const float* rp = w_hh + (size_t)R * HSZ + l * 32;
    #pragma unroll
    for (int c = 0; c < 8; ++c) whh[c] = *(const f32x4*)(rp + c * 4);
  }

  // ---- gate-thread state (tid<16): h_prev, bias_n, igates regs ----
  float hold = 0.f, bn = 0.f, ig_r = 0.f, ig_z = 0.f, ig_n = 0.f;
  if (tid < 16) {
    const int j = wg * 16 + tid;
    hold = init_hidden[j];
    bn   = bias_n[j];
    ig_r = IG[j];
    ig_z = IG[512 + j];
    ig_n = IG[1024 + j];
  }

  __shared__ float h_lds[2][HSZ + 4 * (HSZ >> 5)];
  __shared__ float gsum[48];

  const bool poller = (tid >= 768);
  const int  pt     = tid - 768;          // 0..255
  u32x4 pa, pb, pc, pd, win;

#define ISSUE(Rr) \
  asm volatile("global_load_dwordx4 %0, %1, off sc0 sc1" : "=&v"(Rr) : "v"(lp) : "memory")
#define CHECK(Rr) \
  asm volatile("s_waitcnt vmcnt(3)" : "+v"(Rr)); \
  __builtin_amdgcn_sched_barrier(0); \
  if ((Rr[1] == tt && Rr[3] == tt) || --guard == 0) { win = Rr; break; } \
  ISSUE(Rr)

  for (int t = 0; t < T_STEPS; ++t) {
    const int p  = t & 1;
    const u32 tt = (u32)t;

    // ---- poll h_t (dedicated waves; fresh 4-deep ring, r7-proven) ----
    if (poller) {
      const u64* lp = comm + (size_t)p * HSZ + 2 * pt;
      ISSUE(pa); ISSUE(pb); ISSUE(pc); ISSUE(pd);
      int guard = POLL_GUARD;
      win = pa;
      for (;;) {
        CHECK(pa);
        CHECK(pb);
        CHECK(pc);
        CHECK(pd);
      }
      f32x2 hv;
      hv[0] = __uint_as_float(win[0]);
      hv[1] = __uint_as_float(win[2]);
      *(f32x2*)&h_lds[p][hpad(2 * pt)] = hv;
    }
    // full barrier (implicit vmcnt(0)+lgkmcnt(0) drain): orders h_lds AND
    // drains every wave's outstanding VMEM -- this is what guarantees the
    // producer's previous same-address comm store has completed before the
    // next one is issued (the r12/r13 race is structurally closed here).
    __syncthreads();

    // ---- hh matvec: 32 MAC per mv thread (whh register-resident) ----
    if (mv) {
      float a = 0.f;
      const float* hp = &h_lds[p][l * 36];   // hpad(32l)
      #pragma unroll
      for (int c = 0; c < 8; ++c) {
        f32x4 hv4 = *(const f32x4*)(hp + c * 4);
        #pragma unroll
        for (int u = 0; u < 4; ++u) a += whh[c][u] * hv4[u];
      }
      a = grp_reduce16(a);
      if (l == 0) gsum[g] = a;
    }
    __syncthreads();   // sync2: gsum ready

    // ---- gates + coalesced broadcast + IG prefetch (tid<16 only) ----
    if (tid < 16) {
      const int j = tid;
      const float hr = gsum[j], hz = gsum[16 + j], hn = gsum[32 + j];
      const float reset = __builtin_amdgcn_rcpf(1.0f + __expf(-(ig_r + hr)));
      const float upd   = __builtin_amdgcn_rcpf(1.0f + __expf(-(ig_z + hz)));
      const float e2    = __expf(2.0f * (ig_n + reset * (hn + bn)));
      const float newv  = 1.0f - 2.0f * __builtin_amdgcn_rcpf(1.0f + e2);
      const float hnew  = newv + upd * (hold - newv);
      hold = hnew;
      const float hpair = __shfl(hnew, tid + 1);
      if ((j & 1) == 0) {
        // store FIRST (global critical path); one wave -> coalesced 16B x8
        u64* nbuf = comm + (size_t)((t + 1) & 1) * HSZ;
        u32x4 pk;
        pk[0] = __float_as_uint(hnew);  pk[1] = (u32)(t + 1);
        pk[2] = __float_as_uint(hpair); pk[3] = (u32)(t + 1);
        st16_sys(&nbuf[wg * 16 + j], pk);
        if (wg == 0 && j == 0) out[t] = hnew;
      }
      // IG prefetch for t+1: consumed a full step later; never on the path.
      const size_t bse = (size_t)((t + 1 < T_STEPS) ? (t + 1) : t) * 1536;
      const int jj = wg * 16 + tid;
      ig_r = IG[bse + jj];
      ig_z = IG[bse + 512 + jj];
      ig_n = IG[bse + 1024 + jj];
    }
  }
#undef ISSUE
#undef CHECK
}

// ---------------- Fallback: proven round-7 kernel (ws too small) ------------
#define TPB_FB 1024
__device__ __forceinline__ int xpad(int k) { return k + ((k >> 4) << 2); }

__launch_bounds__(TPB_FB, 1)
__global__ void gru_persistent_fb(const float* __restrict__ input,
                                  const float* __restrict__ init_hidden,
                                  const float* __restrict__ w_ih,
                                  const float* __restrict__ w_hh,
                                  const float* __restrict__ bias,
                                  const float* __restrict__ bias_n,
                                  u64* __restrict__ comm,
                                  float* __restrict__ out)
{
  const int tid = threadIdx.x;
  const int wg  = blockIdx.x;
  const int g   = tid >> 4;
  const int l   = tid & 15;
  const bool mv = (g < 48);
  const int R   = wg * 16 + (g & 15) + 512 * (g >> 4);

  f32x4 whh[8];
  f32x4 wih[4];
  if (mv) {
    const float* rp = w_hh + (size_t)R * HSZ + l * 32;
    #pragma unroll
    for (int c = 0; c < 8; ++c) whh[c] = *(const f32x4*)(rp + c * 4);
    const float* rp2 = w_ih + (size_t)R * INSZ + l * 16;
    #pragma unroll
    for (int c = 0; c < 4; ++c) wih[c] = *(const f32x4*)(rp2 + c * 4);
  }
  float hold = 0.f, b_r = 0.f, b_z = 0.f, b_n = 0.f, bn = 0.f;
  if (tid < 16) {
    const int j = wg * 16 + tid;
    hold = init_hidden[j];
    b_r  = bias[j]; b_z = bias[j + 512]; b_n = bias[j + 1024];
    bn   = bias_n[j];
  }
  __shared__ float h_lds[2][HSZ + 4 * (HSZ >> 5)];
  __shared__ float gsum[48];
  __shared__ float isum[2][48];
  __shared__ float xstage[INSZ + (INSZ >> 4) * 4];

  if (tid >= 64 && tid < 128) {
    const int s = tid - 64;
    f32x4 v = *(const f32x4*)(input + s * 4);
    *(f32x4*)&xstage[xpad(s * 4)] = v;
  }
  __syncthreads();
  if (mv) {
    float a = 0.f;
    #pragma unroll
    for (int c = 0; c < 4; ++c) {
      f32x4 xv = *(const f32x4*)&xstage[20 * l + 4 * c];
      #pragma unroll
      for (int u = 0; u < 4; ++u) a += wih[c][u] * xv[u];
    }
    a = grp_reduce16(a);
    if (l == 0) isum[0][g] = a;
  }
  const bool poller = (tid >= 768);
  const int  pt     = tid - 768;
  u32x4 pa, pb, pc, pd, win;

#define ISSUE(Rr) \
  asm volatile("global_load_dwordx4 %0, %1, off sc0 sc1" : "=&v"(Rr) : "v"(lp) : "memory")
#define CHECK(Rr) \
  asm volatile("s_waitcnt vmcnt(3)" : "+v"(Rr)); \
  __builtin_amdgcn_sched_barrier(0); \
  if ((Rr[1] == tt && Rr[3] == tt) || --guard == 0) { win = Rr; break; } \
  ISSUE(Rr)

  for (int t = 0; t < T_STEPS; ++t) {
    const int p  = t & 1;
    const u32 tt = (u32)t;
    f32x4 xnew = {0.f, 0.f, 0.f, 0.f};
    if (tid >= 64 && tid < 128) {
      const int tn = (t + 1 < T_STEPS) ? (t + 1) : (T_STEPS - 1);
      xnew = *(const f32x4*)(input + (size_t)tn * INSZ + (tid - 64) * 4);
    }
    if (poller) {
      const u64* lp = comm + (size_t)p * HSZ + 2 * pt;
      ISSUE(pa); ISSUE(pb); ISSUE(pc); ISSUE(pd);
      int guard = POLL_GUARD;
      win = pa;
      for (;;) {
        CHECK(pa);
        CHECK(pb);
        CHECK(pc);
        CHECK(pd);
      }
      f32x2 hv;
      hv[0] = __uint_as_float(win[0]);
      hv[1] = __uint_as_float(win[2]);
      *(f32x2*)&h_lds[p][hpad(2 * pt)] = hv;
    }
    __syncthreads();
    if (mv) {
      float a = 0.f;
      const float* hp = &h_lds[p][l * 36];
      #pragma unroll
      for (int c = 0; c < 8; ++c) {
        f32x4 hv4 = *(const f32x4*)(hp + c * 4);
        #pragma unroll
        for (int u = 0; u < 4; ++u) a += whh[c][u] * hv4[u];
      }
      a = grp_reduce16(a);
      if (l == 0) gsum[g] = a;
    }
    if (tid >= 64 && tid < 128) *(f32x4*)&xstage[xpad((tid - 64) * 4)] = xnew;
    __syncthreads();
    if (tid < 16) {
      const int j = tid;
      const float hr = gsum[j], hz = gsum[16 + j], hn = gsum[32 + j];
      const float i_r = isum[p][j], i_z = isum[p][16 + j], i_n = isum[p][32 + j];
      const float reset = __builtin_amdgcn_rcpf(1.0f + __expf(-(i_r + b_r + hr)));
      const float upd   = __builtin_amdgcn_rcpf(1.0f + __expf(-(i_z + b_z + hz)));
      const float e2    = __expf(2.0f * (i_n + b_n + reset * (hn + bn)));
      const float newv  = 1.0f - 2.0f * __builtin_amdgcn_rcpf(1.0f + e2);
      const float hnew  = newv + upd * (hold - newv);
      hold = hnew;
      const float hpair = __shfl(hnew, tid + 1);
      if ((j & 1) == 0) {
        u64* nbuf = comm + (size_t)((t + 1) & 1) * HSZ;
        u32x4 pk;
        pk[0] = __float_as_uint(hnew);  pk[1] = (u32)(t + 1);
        pk[2] = __float_as_uint(hpair); pk[3] = (u32)(t + 1);
        st16_sys(&nbuf[wg * 16 + j], pk);
        if (wg == 0 && j == 0) out[t] = hnew;
      }
    }
    if (mv) {
      float a2 = 0.f;
      #pragma unroll
      for (int c = 0; c < 4; ++c) {
        f32x4 xv = *(const f32x4*)&xstage[20 * l + 4 * c];
        #pragma unroll
        for (int u = 0; u < 4; ++u) a2 += wih[c][u] * xv[u];
      }
      a2 = grp_reduce16(a2);
      if (l == 0) isum[(t + 1) & 1][g] = a2;
    }
  }
#undef ISSUE
#undef CHECK
}

extern "C" void kernel_launch(void* const* d_in, const int* in_sizes, int n_in,
                              void* d_out, int out_size, void* d_ws, size_t ws_size,
                              hipStream_t stream) {
  const float* input  = (const float*)d_in[0];
  const float* h0     = (const float*)d_in[1];
  const float* w_ih   = (const float*)d_in[2];
  const float* w_hh   = (const float*)d_in[3];
  const float* bias   = (const float*)d_in[4];
  const float* bias_n = (const float*)d_in[5];
  float* out = (float*)d_out;

  const size_t IG_BYTES = (size_t)T_STEPS * 1536 * sizeof(float);  // 201.3 MB

  if (ws_size >= IG_BYTES + 16384) {
    float* ig  = (float*)d_ws;
    u64*  comm = (u64*)((char*)d_ws + IG_BYTES);
    hipLaunchKernelGGL(init_comm, dim3(1), dim3(HSZ), 0, stream, comm, h0);
    hipLaunchKernelGGL(igates_gemm, dim3(T_STEPS / 64, 1536 / 64), dim3(256),
                       0, stream, input, w_ih, bias, ig);
    hipLaunchKernelGGL(gru_fast, dim3(NWG), dim3(TPB), 0, stream,
                       ig, h0, w_hh, bias_n, comm, out);
  } else {
    u64* comm = (u64*)d_ws;
    hipLaunchKernelGGL(init_comm, dim3(1), dim3(HSZ), 0, stream, comm, h0);
    hipLaunchKernelGGL(gru_persistent_fb, dim3(NWG), dim3(TPB_FB), 0, stream,
                       input, h0, w_ih, w_hh, bias, bias_n, comm, out);
  }
}